// Round 9
// baseline (319.529 us; speedup 1.0000x reference)
//
#include <hip/hip_runtime.h>
#include <hip/hip_bf16.h>

typedef __bf16 bf16;
typedef __attribute__((ext_vector_type(8))) __bf16 bf16x8;
typedef __attribute__((ext_vector_type(4))) __bf16 bf16x4;
typedef __attribute__((ext_vector_type(4))) float f32x4;
typedef __attribute__((ext_vector_type(4))) int i32x4;

constexpr int SLEN = 2048;
constexpr int DH = 64;
constexpr int NBH = 64;                      // B*H = 4*16
constexpr float SCALE_LOG2E = 0.125f * 1.4426950408889634f;  // (1/sqrt(64)) * log2(e)

// ---- fused pre-pass: K fp32->bf16 (coalesced) + V fp32 [s][d] -> bf16 Vt [d][s] ----
__global__ __launch_bounds__(256) void prep_kv_kernel(
    const float* __restrict__ K, const float* __restrict__ V,
    bf16* __restrict__ Kb, bf16* __restrict__ Vt)
{
    __shared__ float t[64][65];
    const int bh = blockIdx.y;
    const int s0 = blockIdx.x * 64;
    const int tx = threadIdx.x & 63, ty = threadIdx.x >> 6;

    // V tile -> LDS
    const float* vp = V + ((size_t)bh * SLEN + s0) * DH;
    #pragma unroll
    for (int r = ty; r < 64; r += 4) t[r][tx] = vp[(size_t)r * DH + tx];

    // K cast (independent of LDS; overlaps the transpose latency)
    {
        const float* kp = K + ((size_t)bh * SLEN + s0) * DH;
        bf16* kbp = Kb + ((size_t)bh * SLEN + s0) * DH;
        int r = threadIdx.x >> 2, c = (threadIdx.x & 3) * 16;
        const float4* src = (const float4*)(kp + (size_t)r * DH + c);
        float4 a = src[0], b = src[1], c2 = src[2], d = src[3];
        bf16x8 o0, o1;
        o0[0]=(bf16)a.x;  o0[1]=(bf16)a.y;  o0[2]=(bf16)a.z;  o0[3]=(bf16)a.w;
        o0[4]=(bf16)b.x;  o0[5]=(bf16)b.y;  o0[6]=(bf16)b.z;  o0[7]=(bf16)b.w;
        o1[0]=(bf16)c2.x; o1[1]=(bf16)c2.y; o1[2]=(bf16)c2.z; o1[3]=(bf16)c2.w;
        o1[4]=(bf16)d.x;  o1[5]=(bf16)d.y;  o1[6]=(bf16)d.z;  o1[7]=(bf16)d.w;
        *(bf16x8*)(kbp + (size_t)r * DH + c)     = o0;
        *(bf16x8*)(kbp + (size_t)r * DH + c + 8) = o1;
    }

    __syncthreads();
    bf16* op = Vt + (size_t)bh * DH * SLEN + s0;
    #pragma unroll
    for (int r = ty; r < 64; r += 4) op[(size_t)r * SLEN + tx] = (bf16)t[tx][r];
}

// async global->LDS, 16B per lane, dest = wave-uniform base + lane*16
__device__ __forceinline__ void gl_lds16(const void* g, void* l) {
    __builtin_amdgcn_global_load_lds(
        (const __attribute__((address_space(1))) void*)g,
        (__attribute__((address_space(3))) void*)l, 16, 0, 0);
}

// ---- main attention kernel ----
// Identical to R8 except: NO XCD block swizzle (pure A/B attribution round).
// Natural grid dim3(32,64): 32 consecutive blocks share one bh -> natural
// K/V L2 locality under whatever the real dispatch->XCD mapping is.
// 4 waves, 64 q-rows/block, k-tiles of 64, tile t uses LDS buf (t&1).
// Counted-vmcnt schedule: per tile issue {4 gl_lds (K/V), then 4 mask loads};
// end-of-tile sync = s_waitcnt vmcnt(4) lgkmcnt(0) + s_barrier: gl_lds
// retired, DS pipe drained, mask loads stay in flight across the barrier and
// are consumed (register ping-pong mA/mB, statically indexed) next tile.
// K/V LDS rows swizzled byte^=(row&7)<<4 on the GLOBAL SOURCE side (linear
// LDS dest), mirrored on reads. P tile flat 8KB, same swizzle. LDS 40KB ->
// 4 blocks/CU.
// Swapped QK^T: lane (lq,lg) holds scores for q-row lq, k=n*16+lg*4+i.
// masked_fill is 0 (not -inf), |s|<=~7 -> unnormalized exp safe; one divide.
__global__ __launch_bounds__(256, 4) void attn_kernel(
    const float* __restrict__ Q, const int* __restrict__ mask,
    const bf16* __restrict__ Kb, const bf16* __restrict__ Vtb,
    float* __restrict__ out)
{
    __shared__ char KT[2][8192];
    __shared__ char VT[2][8192];
    __shared__ char PT[8192];

    const int bh = blockIdx.y;
    const int qbase = blockIdx.x * 64;
    const int tid = threadIdx.x;
    const int w = tid >> 6, l = tid & 63;
    const int lq = l & 15, lg = l >> 4;

    const char* kgb = (const char*)(Kb + (size_t)bh * SLEN * DH);      // rows 128B
    const char* vgb = (const char*)(Vtb + (size_t)bh * DH * SLEN);     // rows 4096B

    // staging geometry: lane covers (row octet kv_r, swizzled 16B col kv_c)
    const int kv_r = l >> 3;                             // 0..7
    const int kv_c = ((l & 7) * 16) ^ (kv_r << 4);

    // Q B-frags (q-col = lq, k = t*32+lg*8+j), hoisted fp32->bf16
    bf16x8 aq[2];
    {
        const float* qp = Q + ((size_t)bh * SLEN + qbase + w * 16 + lq) * DH + lg * 8;
        #pragma unroll
        for (int t = 0; t < 2; ++t) {
            float4 x = *(const float4*)(qp + t * 32);
            float4 y = *(const float4*)(qp + t * 32 + 4);
            bf16x8 f;
            f[0]=(bf16)x.x; f[1]=(bf16)x.y; f[2]=(bf16)x.z; f[3]=(bf16)x.w;
            f[4]=(bf16)y.x; f[5]=(bf16)y.y; f[6]=(bf16)y.z; f[7]=(bf16)y.w;
            aq[t] = f;
        }
    }

    f32x4 acc[4] = {{0,0,0,0},{0,0,0,0},{0,0,0,0},{0,0,0,0}};
    float dpart = 0.f;
    const int swzk = (lq & 7) << 4;      // read-side XOR, row%8 == lq%8
    const int prow = w * 16 + lq;
    char* pb = PT + prow * 128;
    const int pswz = (prow & 7) << 4;

    const int* mrow = mask + ((size_t)bh * SLEN + qbase + w * 16 + lq) * SLEN;

    // K/V staging for k-tile index t: 4 gl_lds per wave (2 K + 2 V)
    auto stage = [&](int t, int buf) {
        const int kb = t * 64;                           // element offset
        #pragma unroll
        for (int q = 0; q < 2; ++q) {
            int r = (w * 2 + q) * 8 + kv_r;              // tile row 0..63
            gl_lds16(kgb + (size_t)(kb + r) * 128 + kv_c, &KT[buf][(w * 2 + q) * 1024]);
            gl_lds16(vgb + (size_t)r * 4096 + (size_t)kb * 2 + kv_c, &VT[buf][(w * 2 + q) * 1024]);
        }
    };
    auto loadmask = [&](int t, i32x4* m) {
        #pragma unroll
        for (int n = 0; n < 4; ++n)
            m[n] = __builtin_nontemporal_load((const i32x4*)(mrow + t * 64 + n * 16 + lg * 4));
    };
    // one k-tile of compute, reading LDS buf `cur` and mask regs mC
    auto body = [&](int cur, const i32x4* mC) {
        #pragma unroll
        for (int n = 0; n < 4; ++n) {
            f32x4 s = {0, 0, 0, 0};
            #pragma unroll
            for (int t = 0; t < 2; ++t) {
                bf16x8 bk = *(const bf16x8*)&KT[cur][(n * 16 + lq) * 128 + ((t * 64 + lg * 16) ^ swzk)];
                s = __builtin_amdgcn_mfma_f32_16x16x32_bf16(bk, aq[t], s, 0, 0, 0);
            }
            bf16x4 pk;
            #pragma unroll
            for (int i = 0; i < 4; ++i) {
                float e = mC[n][i] ? 0.0f : s[i] * SCALE_LOG2E;
                float p = exp2f(e);
                dpart += p;
                pk[i] = (bf16)p;
            }
            *(bf16x4*)(pb + ((n * 32 + lg * 8) ^ pswz)) = pk;
        }
        #pragma unroll
        for (int n = 0; n < 4; ++n) {
            #pragma unroll
            for (int kk = 0; kk < 2; ++kk) {
                bf16x8 ap = *(const bf16x8*)(pb + ((kk * 64 + lg * 16) ^ pswz));
                bf16x8 bv = *(const bf16x8*)&VT[cur][(n * 16 + lq) * 128 + ((kk * 64 + lg * 16) ^ swzk)];
                acc[n] = __builtin_amdgcn_mfma_f32_16x16x32_bf16(ap, bv, acc[n], 0, 0, 0);
            }
        }
    };
    // counted sync: gl_lds (older) retired, DS pipe drained; 4 mask loads
    // (newest) stay in flight across the barrier.
    auto tile_sync = [&]() {
        asm volatile("s_waitcnt vmcnt(4) lgkmcnt(0)" ::: "memory");
        __builtin_amdgcn_s_barrier();
        __builtin_amdgcn_sched_barrier(0);
    };

    i32x4 mA[4], mB[4];

    // prologue: tile 0 -> buf0, mask0 -> mA
    stage(0, 0);
    __builtin_amdgcn_sched_barrier(0);   // keep mask loads newer than gl_lds
    loadmask(0, mA);
    tile_sync();

    for (int kt = 0; kt < SLEN / 64; kt += 2) {
        // even tile kt: reads buf0/mA; prefetch tile kt+1 -> buf1/mB
        stage(kt + 1, 1);
        __builtin_amdgcn_sched_barrier(0);
        loadmask(kt + 1, mB);
        body(0, mA);
        tile_sync();

        // odd tile kt+1: reads buf1/mB; prefetch tile kt+2 -> buf0/mA
        const bool more = (kt + 2) < (SLEN / 64);
        if (more) {
            stage(kt + 2, 0);
            __builtin_amdgcn_sched_barrier(0);
            loadmask(kt + 2, mA);
        }
        body(1, mB);
        if (more) tile_sync();
    }

    // denom: lanes {lq, lq+16, lq+32, lq+48} hold partials for q-row lq
    dpart += __shfl_xor(dpart, 16, 64);
    dpart += __shfl_xor(dpart, 32, 64);
    float dinv = 1.0f / dpart;

    float di[4];
    #pragma unroll
    for (int i = 0; i < 4; ++i) di[i] = __shfl(dinv, lg * 4 + i, 64);

    float* op = out + ((size_t)bh * SLEN + qbase + w * 16) * DH;
    #pragma unroll
    for (int n = 0; n < 4; ++n) {
        #pragma unroll
        for (int i = 0; i < 4; ++i)
            op[(size_t)(lg * 4 + i) * DH + n * 16 + lq] = acc[n][i] * di[i];
    }
}

extern "C" void kernel_launch(void* const* d_in, const int* in_sizes, int n_in,
                              void* d_out, int out_size, void* d_ws, size_t ws_size,
                              hipStream_t stream) {
    const float* Q    = (const float*)d_in[0];
    const float* K    = (const float*)d_in[1];
    const float* V    = (const float*)d_in[2];
    const int*   mask = (const int*)d_in[3];
    float* out = (float*)d_out;

    bf16* Kb  = (bf16*)d_ws;                       // 16 MB
    bf16* Vtb = Kb + (size_t)NBH * SLEN * DH;      // 16 MB

    prep_kv_kernel<<<dim3(SLEN / 64, NBH), 256, 0, stream>>>(K, V, Kb, Vtb);
    attn_kernel<<<dim3(SLEN / 64, NBH), 256, 0, stream>>>(Q, mask, Kb, Vtb, out);
}

// Round 11
// 314.214 us; speedup vs baseline: 1.0169x; 1.0169x over previous
//
#include <hip/hip_runtime.h>
#include <hip/hip_bf16.h>

typedef __bf16 bf16;
typedef __attribute__((ext_vector_type(8))) __bf16 bf16x8;
typedef __attribute__((ext_vector_type(4))) __bf16 bf16x4;
typedef __attribute__((ext_vector_type(4))) float f32x4;
typedef __attribute__((ext_vector_type(4))) int i32x4;
typedef __attribute__((ext_vector_type(4))) short s16x4;

constexpr int SLEN = 2048;
constexpr int DH = 64;
constexpr int NBH = 64;                      // B*H = 4*16
constexpr float SCALE_LOG2E = 0.125f * 1.4426950408889634f;  // (1/sqrt(64)) * log2(e)

// ---- fused pre-pass: K fp32->bf16 (coalesced) + V fp32 [s][d] -> bf16 Vt [d][s] ----
__global__ __launch_bounds__(256) void prep_kv_kernel(
    const float* __restrict__ K, const float* __restrict__ V,
    bf16* __restrict__ Kb, bf16* __restrict__ Vt)
{
    __shared__ float t[64][65];
    const int bh = blockIdx.y;
    const int s0 = blockIdx.x * 64;
    const int tx = threadIdx.x & 63, ty = threadIdx.x >> 6;

    // V tile -> LDS
    const float* vp = V + ((size_t)bh * SLEN + s0) * DH;
    #pragma unroll
    for (int r = ty; r < 64; r += 4) t[r][tx] = vp[(size_t)r * DH + tx];

    // K cast (independent of LDS; overlaps the transpose latency)
    {
        const float* kp = K + ((size_t)bh * SLEN + s0) * DH;
        bf16* kbp = Kb + ((size_t)bh * SLEN + s0) * DH;
        int r = threadIdx.x >> 2, c = (threadIdx.x & 3) * 16;
        const float4* src = (const float4*)(kp + (size_t)r * DH + c);
        float4 a = src[0], b = src[1], c2 = src[2], d = src[3];
        bf16x8 o0, o1;
        o0[0]=(bf16)a.x;  o0[1]=(bf16)a.y;  o0[2]=(bf16)a.z;  o0[3]=(bf16)a.w;
        o0[4]=(bf16)b.x;  o0[5]=(bf16)b.y;  o0[6]=(bf16)b.z;  o0[7]=(bf16)b.w;
        o1[0]=(bf16)c2.x; o1[1]=(bf16)c2.y; o1[2]=(bf16)c2.z; o1[3]=(bf16)c2.w;
        o1[4]=(bf16)d.x;  o1[5]=(bf16)d.y;  o1[6]=(bf16)d.z;  o1[7]=(bf16)d.w;
        *(bf16x8*)(kbp + (size_t)r * DH + c)     = o0;
        *(bf16x8*)(kbp + (size_t)r * DH + c + 8) = o1;
    }

    __syncthreads();
    bf16* op = Vt + (size_t)bh * DH * SLEN + s0;
    #pragma unroll
    for (int r = ty; r < 64; r += 4) op[(size_t)r * SLEN + tx] = (bf16)t[tx][r];
}

// async global->LDS, 16B per lane, dest = wave-uniform base + lane*16
__device__ __forceinline__ void gl_lds16(const void* g, void* l) {
    __builtin_amdgcn_global_load_lds(
        (const __attribute__((address_space(1))) void*)g,
        (__attribute__((address_space(3))) void*)l, 16, 0, 0);
}

// 16x16x16 bf16 MFMA (instruction exists on gfx950: cdna4_isa §10).
// Builtin carries the legacy gfx90a name *bf16_1k; guard with __has_builtin
// and fall back to inline asm (with conservative hazard s_nops) if absent.
__device__ __forceinline__ f32x4 pv_mfma(bf16x4 a, bf16x4 b, f32x4 c) {
#if __has_builtin(__builtin_amdgcn_mfma_f32_16x16x16bf16_1k)
    return __builtin_amdgcn_mfma_f32_16x16x16bf16_1k(
        __builtin_bit_cast(s16x4, a), __builtin_bit_cast(s16x4, b), c, 0, 0, 0);
#else
    f32x4 d;
    asm("s_nop 1\n\t"
        "v_mfma_f32_16x16x16_bf16 %0, %1, %2, %3\n\t"
        "s_nop 7"
        : "=v"(d) : "v"(a), "v"(b), "v"(c));
    return d;
#endif
}

// ---- main attention kernel ----
// vs R8: P never touches LDS. QK^T's S^T C-frag (q=l&15, k=(l>>4)*4+i per
// 16-k subtile) IS the A-frag layout of v_mfma_f32_16x16x16_bf16, so PV
// consumes P directly from registers: acc[nn] += pv_mfma(p[n], vfrag).
// V B-frags are b64 LDS reads (k=(l>>4)*4+i, col=l&15 -> 8B contiguous in
// Vt row). Deletes the P write->lgkm->read serialization from the per-tile
// critical path and frees PT: LDS 32KB. launch_bounds kept at (256,4) to
// isolate this one change vs R8 (occupancy-5 is the next lever).
// Counted-vmcnt schedule (unchanged): per tile {4 gl_lds, 4 mask loads};
// sync = s_waitcnt vmcnt(4) lgkmcnt(0) + s_barrier; mask regs ping-pong.
// K/V LDS rows swizzled byte^=(row&7)<<4 on the GLOBAL SOURCE side, mirrored
// on reads. XCD-bijective block swizzle (R8/R9 A/B: +7us) restored.
// masked_fill is 0 (not -inf), |s|<=~7 -> unnormalized exp safe; one divide.
__global__ __launch_bounds__(256, 4) void attn_kernel(
    const float* __restrict__ Q, const int* __restrict__ mask,
    const bf16* __restrict__ Kb, const bf16* __restrict__ Vtb,
    float* __restrict__ out)
{
    __shared__ char KT[2][8192];
    __shared__ char VT[2][8192];

    // XCD-aware bijective swizzle (2048 blocks, 2048%8==0): XCD x owns bh 8x..8x+7
    const int h = blockIdx.x;
    const int logical = (h & 7) * 256 + (h >> 3);
    const int bh = logical >> 5;
    const int qbase = (logical & 31) * 64;
    const int tid = threadIdx.x;
    const int w = tid >> 6, l = tid & 63;
    const int lq = l & 15, lg = l >> 4;

    const char* kgb = (const char*)(Kb + (size_t)bh * SLEN * DH);      // rows 128B
    const char* vgb = (const char*)(Vtb + (size_t)bh * DH * SLEN);     // rows 4096B

    // staging geometry: lane covers (row octet kv_r, swizzled 16B col kv_c)
    const int kv_r = l >> 3;                             // 0..7
    const int kv_c = ((l & 7) * 16) ^ (kv_r << 4);

    // Q B-frags (q-col = lq, k = t*32+lg*8+j), hoisted fp32->bf16
    bf16x8 aq[2];
    {
        const float* qp = Q + ((size_t)bh * SLEN + qbase + w * 16 + lq) * DH + lg * 8;
        #pragma unroll
        for (int t = 0; t < 2; ++t) {
            float4 x = *(const float4*)(qp + t * 32);
            float4 y = *(const float4*)(qp + t * 32 + 4);
            bf16x8 f;
            f[0]=(bf16)x.x; f[1]=(bf16)x.y; f[2]=(bf16)x.z; f[3]=(bf16)x.w;
            f[4]=(bf16)y.x; f[5]=(bf16)y.y; f[6]=(bf16)y.z; f[7]=(bf16)y.w;
            aq[t] = f;
        }
    }

    f32x4 acc[4] = {{0,0,0,0},{0,0,0,0},{0,0,0,0},{0,0,0,0}};
    float dpart = 0.f;
    const int swzk = (lq & 7) << 4;      // read-side XOR, row%8 == lq%8

    const int* mrow = mask + ((size_t)bh * SLEN + qbase + w * 16 + lq) * SLEN;

    // K/V staging for k-tile index t: 4 gl_lds per wave (2 K + 2 V)
    auto stage = [&](int t, int buf) {
        const int kb = t * 64;                           // element offset
        #pragma unroll
        for (int q = 0; q < 2; ++q) {
            int r = (w * 2 + q) * 8 + kv_r;              // tile row 0..63
            gl_lds16(kgb + (size_t)(kb + r) * 128 + kv_c, &KT[buf][(w * 2 + q) * 1024]);
            gl_lds16(vgb + (size_t)r * 4096 + (size_t)kb * 2 + kv_c, &VT[buf][(w * 2 + q) * 1024]);
        }
    };
    auto loadmask = [&](int t, i32x4* m) {
        #pragma unroll
        for (int n = 0; n < 4; ++n)
            m[n] = __builtin_nontemporal_load((const i32x4*)(mrow + t * 64 + n * 16 + lg * 4));
    };
    // one k-tile of compute, reading LDS buf `cur` and mask regs mC
    auto body = [&](int cur, const i32x4* mC) {
        // QK^T: S^T subtile n -> p[n] (bf16x4, q=lq, k=n*16+lg*4+i)
        bf16x4 p[4];
        #pragma unroll
        for (int n = 0; n < 4; ++n) {
            f32x4 s = {0, 0, 0, 0};
            #pragma unroll
            for (int t = 0; t < 2; ++t) {
                bf16x8 bk = *(const bf16x8*)&KT[cur][(n * 16 + lq) * 128 + ((t * 64 + lg * 16) ^ swzk)];
                s = __builtin_amdgcn_mfma_f32_16x16x32_bf16(bk, aq[t], s, 0, 0, 0);
            }
            #pragma unroll
            for (int i = 0; i < 4; ++i) {
                float e = mC[n][i] ? 0.0f : s[i] * SCALE_LOG2E;
                float pe = exp2f(e);
                dpart += pe;
                p[n][i] = (bf16)pe;
            }
        }
        // PV: acc[nn] += sum_n P_frag(n) x V_frag(nn,n), all in registers;
        // V B-frag = b64 read: row d = nn*16+lq, k-bytes n*32+lg*8 (^ swz)
        #pragma unroll
        for (int nn = 0; nn < 4; ++nn) {
            #pragma unroll
            for (int n = 0; n < 4; ++n) {
                bf16x4 bv = *(const bf16x4*)&VT[cur][(nn * 16 + lq) * 128 + ((n * 32 + lg * 8) ^ swzk)];
                acc[nn] = pv_mfma(p[n], bv, acc[nn]);
            }
        }
    };
    // counted sync: gl_lds (older) retired, DS pipe drained; 4 mask loads
    // (newest) stay in flight across the barrier.
    auto tile_sync = [&]() {
        asm volatile("s_waitcnt vmcnt(4) lgkmcnt(0)" ::: "memory");
        __builtin_amdgcn_s_barrier();
        __builtin_amdgcn_sched_barrier(0);
    };

    i32x4 mA[4], mB[4];

    // prologue: tile 0 -> buf0, mask0 -> mA
    stage(0, 0);
    __builtin_amdgcn_sched_barrier(0);   // keep mask loads newer than gl_lds
    loadmask(0, mA);
    tile_sync();

    for (int kt = 0; kt < SLEN / 64; kt += 2) {
        // even tile kt: reads buf0/mA; prefetch tile kt+1 -> buf1/mB
        stage(kt + 1, 1);
        __builtin_amdgcn_sched_barrier(0);
        loadmask(kt + 1, mB);
        body(0, mA);
        tile_sync();

        // odd tile kt+1: reads buf1/mB; prefetch tile kt+2 -> buf0/mA
        const bool more = (kt + 2) < (SLEN / 64);
        if (more) {
            stage(kt + 2, 0);
            __builtin_amdgcn_sched_barrier(0);
            loadmask(kt + 2, mA);
        }
        body(1, mB);
        if (more) tile_sync();
    }

    // denom: lanes {lq, lq+16, lq+32, lq+48} hold partials for q-row lq
    dpart += __shfl_xor(dpart, 16, 64);
    dpart += __shfl_xor(dpart, 32, 64);
    float dinv = 1.0f / dpart;

    float di[4];
    #pragma unroll
    for (int i = 0; i < 4; ++i) di[i] = __shfl(dinv, lg * 4 + i, 64);

    float* op = out + ((size_t)bh * SLEN + qbase + w * 16) * DH;
    #pragma unroll
    for (int n = 0; n < 4; ++n) {
        #pragma unroll
        for (int i = 0; i < 4; ++i)
            op[(size_t)(lg * 4 + i) * DH + n * 16 + lq] = acc[n][i] * di[i];
    }
}

extern "C" void kernel_launch(void* const* d_in, const int* in_sizes, int n_in,
                              void* d_out, int out_size, void* d_ws, size_t ws_size,
                              hipStream_t stream) {
    const float* Q    = (const float*)d_in[0];
    const float* K    = (const float*)d_in[1];
    const float* V    = (const float*)d_in[2];
    const int*   mask = (const int*)d_in[3];
    float* out = (float*)d_out;

    bf16* Kb  = (bf16*)d_ws;                       // 16 MB
    bf16* Vtb = Kb + (size_t)NBH * SLEN * DH;      // 16 MB

    prep_kv_kernel<<<dim3(SLEN / 64, NBH), 256, 0, stream>>>(K, V, Kb, Vtb);
    attn_kernel<<<2048, 256, 0, stream>>>(Q, mask, Kb, Vtb, out);
}

// Round 12
// 305.760 us; speedup vs baseline: 1.0450x; 1.0276x over previous
//
#include <hip/hip_runtime.h>
#include <hip/hip_bf16.h>

typedef __bf16 bf16;
typedef __attribute__((ext_vector_type(8))) __bf16 bf16x8;
typedef __attribute__((ext_vector_type(4))) __bf16 bf16x4;
typedef __attribute__((ext_vector_type(4))) float f32x4;
typedef __attribute__((ext_vector_type(4))) int i32x4;
typedef __attribute__((ext_vector_type(4))) short s16x4;

constexpr int SLEN = 2048;
constexpr int DH = 64;
constexpr int NBH = 64;                      // B*H = 4*16
constexpr int NT = SLEN / 64;                // 32 k-tiles
constexpr float SCALE_LOG2E = 0.125f * 1.4426950408889634f;  // (1/sqrt(64)) * log2(e)

// ---- fused pre-pass: K fp32->bf16 (coalesced) + V fp32 [s][d] -> bf16 Vt [d][s] ----
__global__ __launch_bounds__(256) void prep_kv_kernel(
    const float* __restrict__ K, const float* __restrict__ V,
    bf16* __restrict__ Kb, bf16* __restrict__ Vt)
{
    __shared__ float t[64][65];
    const int bh = blockIdx.y;
    const int s0 = blockIdx.x * 64;
    const int tx = threadIdx.x & 63, ty = threadIdx.x >> 6;

    // V tile -> LDS
    const float* vp = V + ((size_t)bh * SLEN + s0) * DH;
    #pragma unroll
    for (int r = ty; r < 64; r += 4) t[r][tx] = vp[(size_t)r * DH + tx];

    // K cast (independent of LDS; overlaps the transpose latency)
    {
        const float* kp = K + ((size_t)bh * SLEN + s0) * DH;
        bf16* kbp = Kb + ((size_t)bh * SLEN + s0) * DH;
        int r = threadIdx.x >> 2, c = (threadIdx.x & 3) * 16;
        const float4* src = (const float4*)(kp + (size_t)r * DH + c);
        float4 a = src[0], b = src[1], c2 = src[2], d = src[3];
        bf16x8 o0, o1;
        o0[0]=(bf16)a.x;  o0[1]=(bf16)a.y;  o0[2]=(bf16)a.z;  o0[3]=(bf16)a.w;
        o0[4]=(bf16)b.x;  o0[5]=(bf16)b.y;  o0[6]=(bf16)b.z;  o0[7]=(bf16)b.w;
        o1[0]=(bf16)c2.x; o1[1]=(bf16)c2.y; o1[2]=(bf16)c2.z; o1[3]=(bf16)c2.w;
        o1[4]=(bf16)d.x;  o1[5]=(bf16)d.y;  o1[6]=(bf16)d.z;  o1[7]=(bf16)d.w;
        *(bf16x8*)(kbp + (size_t)r * DH + c)     = o0;
        *(bf16x8*)(kbp + (size_t)r * DH + c + 8) = o1;
    }

    __syncthreads();
    bf16* op = Vt + (size_t)bh * DH * SLEN + s0;
    #pragma unroll
    for (int r = ty; r < 64; r += 4) op[(size_t)r * SLEN + tx] = (bf16)t[tx][r];
}

// async global->LDS, 16B per lane, dest = wave-uniform base + lane*16
__device__ __forceinline__ void gl_lds16(const void* g, void* l) {
    __builtin_amdgcn_global_load_lds(
        (const __attribute__((address_space(1))) void*)g,
        (__attribute__((address_space(3))) void*)l, 16, 0, 0);
}

// 16x16x16 bf16 MFMA (instruction exists on gfx950: cdna4_isa §10).
// Builtin carries the legacy gfx90a name *bf16_1k; guard with __has_builtin
// and fall back to inline asm (with conservative hazard s_nops) if absent.
__device__ __forceinline__ f32x4 pv_mfma(bf16x4 a, bf16x4 b, f32x4 c) {
#if __has_builtin(__builtin_amdgcn_mfma_f32_16x16x16bf16_1k)
    return __builtin_amdgcn_mfma_f32_16x16x16bf16_1k(
        __builtin_bit_cast(s16x4, a), __builtin_bit_cast(s16x4, b), c, 0, 0, 0);
#else
    f32x4 d;
    asm("s_nop 1\n\t"
        "v_mfma_f32_16x16x16_bf16 %0, %1, %2, %3\n\t"
        "s_nop 7"
        : "=v"(d) : "v"(a), "v"(b), "v"(c));
    return d;
#endif
}

// ---- main attention kernel ----
// vs R11 (one goal: 5 blocks/CU): LDS is 32KB/block (KT+VT dbuf, no P tile:
// PV consumes P from registers via 16x16x16 MFMA), 5 x 32KB = 160KB exactly,
// launch_bounds(256,5) caps VGPR at ~102. To fit: mask ping-pong (32 regs)
// replaced by nibble-compress — per tile, the 4 raw i32x4 mask loads (16
// regs, single buffer) are compressed to 4 packed u32 nibbles BEFORE issuing
// next tile's mask loads, so loads still go out a full tile early and the
// raw regs are immediately reusable. Compress waits only on the OLDER mask
// loads (vmcnt leaves this tile's gl_lds in flight).
// Counted-vmcnt schedule: per tile {4 gl_lds, [compress], 4 mask loads};
// sync = s_waitcnt vmcnt(4) lgkmcnt(0) + s_barrier.
// K/V LDS rows swizzled byte^=(row&7)<<4 on the GLOBAL SOURCE side, mirrored
// on reads. XCD-bijective block swizzle (R8/R9 A/B: +7us).
// Swapped QK^T: lane (lq,lg) holds scores for q-row lq, k=n*16+lg*4+i.
// masked_fill is 0 (not -inf), |s|<=~7 -> unnormalized exp safe; one divide.
__global__ __launch_bounds__(256, 5) void attn_kernel(
    const float* __restrict__ Q, const int* __restrict__ mask,
    const bf16* __restrict__ Kb, const bf16* __restrict__ Vtb,
    float* __restrict__ out)
{
    __shared__ char KT[2][8192];
    __shared__ char VT[2][8192];

    // XCD-aware bijective swizzle (2048 blocks, 2048%8==0): XCD x owns bh 8x..8x+7
    const int h = blockIdx.x;
    const int logical = (h & 7) * 256 + (h >> 3);
    const int bh = logical >> 5;
    const int qbase = (logical & 31) * 64;
    const int tid = threadIdx.x;
    const int w = tid >> 6, l = tid & 63;
    const int lq = l & 15, lg = l >> 4;

    const char* kgb = (const char*)(Kb + (size_t)bh * SLEN * DH);      // rows 128B
    const char* vgb = (const char*)(Vtb + (size_t)bh * DH * SLEN);     // rows 4096B

    // staging geometry: lane covers (row octet kv_r, swizzled 16B col kv_c)
    const int kv_r = l >> 3;                             // 0..7
    const int kv_c = ((l & 7) * 16) ^ (kv_r << 4);

    // Q B-frags (q-col = lq, k = t*32+lg*8+j), hoisted fp32->bf16
    bf16x8 aq[2];
    {
        const float* qp = Q + ((size_t)bh * SLEN + qbase + w * 16 + lq) * DH + lg * 8;
        #pragma unroll
        for (int t = 0; t < 2; ++t) {
            float4 x = *(const float4*)(qp + t * 32);
            float4 y = *(const float4*)(qp + t * 32 + 4);
            bf16x8 f;
            f[0]=(bf16)x.x; f[1]=(bf16)x.y; f[2]=(bf16)x.z; f[3]=(bf16)x.w;
            f[4]=(bf16)y.x; f[5]=(bf16)y.y; f[6]=(bf16)y.z; f[7]=(bf16)y.w;
            aq[t] = f;
        }
    }

    f32x4 acc[4] = {{0,0,0,0},{0,0,0,0},{0,0,0,0},{0,0,0,0}};
    float dpart = 0.f;
    const int swzk = (lq & 7) << 4;      // read-side XOR, row%8 == lq%8

    const int* mrow = mask + ((size_t)bh * SLEN + qbase + w * 16 + lq) * SLEN;

    // K/V staging for k-tile index t: 4 gl_lds per wave (2 K + 2 V)
    auto stage = [&](int t, int buf) {
        const int kb = t * 64;                           // element offset
        #pragma unroll
        for (int q = 0; q < 2; ++q) {
            int r = (w * 2 + q) * 8 + kv_r;              // tile row 0..63
            gl_lds16(kgb + (size_t)(kb + r) * 128 + kv_c, &KT[buf][(w * 2 + q) * 1024]);
            gl_lds16(vgb + (size_t)r * 4096 + (size_t)kb * 2 + kv_c, &VT[buf][(w * 2 + q) * 1024]);
        }
    };
    auto loadmask = [&](int t, i32x4* m) {
        #pragma unroll
        for (int n = 0; n < 4; ++n)
            m[n] = __builtin_nontemporal_load((const i32x4*)(mrow + t * 64 + n * 16 + lg * 4));
    };
    // one k-tile of compute: LDS buf `cur`, packed mask nibbles pm[4]
    auto body = [&](int cur, const unsigned* pm) {
        // QK^T: S^T subtile n -> p[n] (bf16x4, q=lq, k=n*16+lg*4+i)
        bf16x4 p[4];
        #pragma unroll
        for (int n = 0; n < 4; ++n) {
            f32x4 s = {0, 0, 0, 0};
            #pragma unroll
            for (int t = 0; t < 2; ++t) {
                bf16x8 bk = *(const bf16x8*)&KT[cur][(n * 16 + lq) * 128 + ((t * 64 + lg * 16) ^ swzk)];
                s = __builtin_amdgcn_mfma_f32_16x16x32_bf16(bk, aq[t], s, 0, 0, 0);
            }
            #pragma unroll
            for (int i = 0; i < 4; ++i) {
                float pe = exp2f(s[i] * SCALE_LOG2E);
                pe = ((pm[n] >> i) & 1u) ? 1.0f : pe;    // masked score 0 -> weight 1
                dpart += pe;
                p[n][i] = (bf16)pe;
            }
        }
        // PV: acc[nn] += sum_n P_frag(n) x V_frag(nn,n), all in registers;
        // V B-frag = b64 read: row d = nn*16+lq, k-bytes n*32+lg*8 (^ swz)
        #pragma unroll
        for (int nn = 0; nn < 4; ++nn) {
            #pragma unroll
            for (int n = 0; n < 4; ++n) {
                bf16x4 bv = *(const bf16x4*)&VT[cur][(nn * 16 + lq) * 128 + ((n * 32 + lg * 8) ^ swzk)];
                acc[nn] = pv_mfma(p[n], bv, acc[nn]);
            }
        }
    };
    // counted sync: gl_lds (older) retired, DS pipe drained; 4 mask loads
    // (newest) stay in flight across the barrier.
    auto tile_sync = [&]() {
        asm volatile("s_waitcnt vmcnt(4) lgkmcnt(0)" ::: "memory");
        __builtin_amdgcn_s_barrier();
        __builtin_amdgcn_sched_barrier(0);
    };

    i32x4 raw[4];        // single mask load buffer (freed each tile by compress)
    unsigned pm[4];      // packed nibbles for the current tile

    // prologue: tile 0 -> buf0, mask0 -> raw
    stage(0, 0);
    __builtin_amdgcn_sched_barrier(0);   // keep mask loads newer than gl_lds
    loadmask(0, raw);
    tile_sync();

    int cur = 0;
    for (int kt = 0; kt < NT; ++kt) {
        const bool more = (kt + 1) < NT;                 // wave-uniform
        if (more) stage(kt + 1, cur ^ 1);                // K/V prefetch first
        __builtin_amdgcn_sched_barrier(0);
        // compress raw (tile kt, loaded one tile ago) -> pm; frees raw
        #pragma unroll
        for (int n = 0; n < 4; ++n)
            pm[n] = (raw[n][0] != 0 ? 1u : 0u) | (raw[n][1] != 0 ? 2u : 0u)
                  | (raw[n][2] != 0 ? 4u : 0u) | (raw[n][3] != 0 ? 8u : 0u);
        if (more) loadmask(kt + 1, raw);                 // next-tile masks, early
        __builtin_amdgcn_sched_barrier(0);
        body(cur, pm);
        if (more) { tile_sync(); cur ^= 1; }
    }

    // denom: lanes {lq, lq+16, lq+32, lq+48} hold partials for q-row lq
    dpart += __shfl_xor(dpart, 16, 64);
    dpart += __shfl_xor(dpart, 32, 64);
    float dinv = 1.0f / dpart;

    float di[4];
    #pragma unroll
    for (int i = 0; i < 4; ++i) di[i] = __shfl(dinv, lg * 4 + i, 64);

    float* op = out + ((size_t)bh * SLEN + qbase + w * 16) * DH;
    #pragma unroll
    for (int n = 0; n < 4; ++n) {
        #pragma unroll
        for (int i = 0; i < 4; ++i)
            op[(size_t)(lg * 4 + i) * DH + n * 16 + lq] = acc[n][i] * di[i];
    }
}

extern "C" void kernel_launch(void* const* d_in, const int* in_sizes, int n_in,
                              void* d_out, int out_size, void* d_ws, size_t ws_size,
                              hipStream_t stream) {
    const float* Q    = (const float*)d_in[0];
    const float* K    = (const float*)d_in[1];
    const float* V    = (const float*)d_in[2];
    const int*   mask = (const int*)d_in[3];
    float* out = (float*)d_out;

    bf16* Kb  = (bf16*)d_ws;                       // 16 MB
    bf16* Vtb = Kb + (size_t)NBH * SLEN * DH;      // 16 MB

    prep_kv_kernel<<<dim3(SLEN / 64, NBH), 256, 0, stream>>>(K, V, Kb, Vtb);
    attn_kernel<<<2048, 256, 0, stream>>>(Q, mask, Kb, Vtb, out);
}